// Round 10
// baseline (75.836 us; speedup 1.0000x reference)
//
#include <hip/hip_runtime.h>
#include <math.h>

#define ALPHA 0.3f
#define KN 32

__device__ __forceinline__ float leaky_f(float x) { return x >= 0.f ? x : ALPHA * x; }

// ---------------------------------------------------------------------------
// K_A: 16 nodes/block (4 waves x 2 node-pairs):
//   h0[n,h] = leaky( sum_c emb[n,c]*Q0w[c,h] + Q0b[h] )
//   wcache[n,k] = wmat[n, nbr[n,k]]   (issued FIRST; latency hides under GEMV)
// Q0^T staged in LDS as float4 chunks, XOR-swizzled (T2) for bank spread.
// ---------------------------------------------------------------------------
__global__ __launch_bounds__(256) void k_dense_gather(
    const float* __restrict__ X,
    const float* __restrict__ Qw,   // 64 x 64, row-major [c][h]
    const float* __restrict__ Qb,
    const float* __restrict__ wmat,
    const int*  __restrict__ nbr,
    float* __restrict__ wcache,     // may be null
    float* __restrict__ Hout,
    int N)
{
    __shared__ float4 sQT[64][16];  // Q^T: sQT[h][c4 ^ (h&7)] = Q[4c4..][h], 16 KB
    __shared__ float  sX[4][2][64]; // 2 KB

    const int tid  = threadIdx.x;
    const int wid  = tid >> 6;
    const int lane = tid & 63;
    const int bs   = blockIdx.x * 16;

    // --- random gathers first: 512 (node,k) entries = 2 per thread ---
    int gid[2]; float gw[2];
    #pragma unroll
    for (int u = 0; u < 2; ++u) {
        int e = tid + u * 256;
        int n = bs + (e >> 5); if (n >= N) n = N - 1;
        gid[u] = nbr[(size_t)n * KN + (e & 31)];
    }
    #pragma unroll
    for (int u = 0; u < 2; ++u) {
        int e = tid + u * 256;
        int n = bs + (e >> 5); if (n >= N) n = N - 1;
        gw[u] = wmat[(size_t)n * (size_t)N + gid[u]];
    }

    // --- stage Q^T (transpose scatter), overlapped with gathers ---
    {
        const float4* s = (const float4*)Qw;
        #pragma unroll
        for (int i = 0; i < 4; ++i) {
            int idx = i * 256 + tid;        // [0,1024)
            float4 v = s[idx];
            int c  = idx >> 4;              // [0,64)
            int h4 = idx & 15;
            #pragma unroll
            for (int u = 0; u < 4; ++u) {
                int h = h4 * 4 + u;
                ((float*)&sQT[h][(c >> 2) ^ (h & 7)])[c & 3] = (&v.x)[u];
            }
        }
    }
    __syncthreads();

    const float qb = Qb[lane];
    #pragma unroll
    for (int p = 0; p < 2; ++p) {
        int n0 = bs + p * 8 + wid * 2;
        int n1 = n0 + 1;
        int m0 = n0 < N ? n0 : N - 1;
        int m1 = n1 < N ? n1 : N - 1;
        sX[wid][0][lane] = X[(size_t)m0 * 64 + lane];   // wave-local
        sX[wid][1][lane] = X[(size_t)m1 * 64 + lane];
        const float4* x40 = (const float4*)sX[wid][0];
        const float4* x41 = (const float4*)sX[wid][1];

        float a0 = qb, a1 = qb;
        #pragma unroll
        for (int c4 = 0; c4 < 16; ++c4) {
            float4 wv = sQT[lane][c4 ^ (lane & 7)];
            float4 v0 = x40[c4], v1 = x41[c4];
            #pragma unroll
            for (int u = 0; u < 4; ++u) {
                a0 = fmaf((&v0.x)[u], (&wv.x)[u], a0);
                a1 = fmaf((&v1.x)[u], (&wv.x)[u], a1);
            }
        }
        if (n0 < N) Hout[(size_t)n0 * 64 + lane] = leaky_f(a0);
        if (n1 < N) Hout[(size_t)n1 * 64 + lane] = leaky_f(a1);
    }

    // --- persist gathered weights (coalesced) ---
    if (wcache) {
        #pragma unroll
        for (int u = 0; u < 2; ++u) {
            int e = tid + u * 256;
            if (bs + (e >> 5) < N) wcache[(size_t)bs * KN + e] = gw[u];
        }
    }
}

// ---------------------------------------------------------------------------
// K_B/K_C: conv layer, 8 nodes/block = 4 waves x 1 node-PAIR each.
//   lanes 0..31 hold node-a (id,w), lanes 32..63 node-b; agg via __shfl.
//   W^T staged in LDS float4 XOR-swizzled; GEMV processes both nodes per
//   W read. FUSE: h1 = leaky(out0 . Q1 + b) via __shfl + L1-resident Q1w.
// In-place safe (OUT may alias X): wave reads own rows before writing them.
// wcache is read-only here (K_A produces it); mode 0 = re-gather fallback.
// ---------------------------------------------------------------------------
template<bool FUSE>
__global__ __launch_bounds__(256) void k_conv(
    const float* __restrict__ X,
    const float* __restrict__ Hbuf,
    const float* __restrict__ Wmat,
    const float* __restrict__ wcache,
    const int*  __restrict__ nbr,
    const float* __restrict__ Ww,    // 128 x 64 row-major [c][h]
    const float* __restrict__ Wb,
    const float* __restrict__ Q1w,   // 64 x 64 (FUSE)
    const float* __restrict__ Q1b,   // 64     (FUSE)
    float* __restrict__ OUT,
    float* __restrict__ H1out,
    int N, int mode)
{
    __shared__ float4 sWT[64][32];  // W^T: sWT[h][c4 ^ (h&7)], 32 KB
    __shared__ float  sx[4][2][64]; // 2 KB
    __shared__ float  sa[4][2][64]; // 2 KB  => 36 KB total, 4 blocks/CU

    const int tid  = threadIdx.x;
    const int wid  = tid >> 6;
    const int lane = tid & 63;
    const int bs   = blockIdx.x * 8;

    const int na = bs + wid * 2;
    const int nb = na + 1;
    const int ma = na < N ? na : N - 1;
    const int mb = nb < N ? nb : N - 1;

    // --- issue all irregular loads FIRST ---
    // full wave: lanes 0..31 -> node a entries, lanes 32..63 -> node b
    const int  myn = (lane < 32) ? ma : mb;
    const int  myk = lane & 31;
    const int  id  = nbr[(size_t)myn * KN + myk];
    const float w  = (mode == 1) ? wcache[(size_t)myn * KN + myk]
                                 : Wmat[(size_t)myn * (size_t)N + id];
    float xa = X[(size_t)ma * 64 + lane];
    float xb = X[(size_t)mb * 64 + lane];

    // --- stage W^T (transpose scatter) while loads are in flight ---
    {
        const float4* s = (const float4*)Ww;
        #pragma unroll
        for (int i = 0; i < 8; ++i) {
            int idx = i * 256 + tid;        // [0,2048)
            float4 v = s[idx];
            int c  = idx >> 4;              // [0,128)
            int h4 = idx & 15;
            #pragma unroll
            for (int u = 0; u < 4; ++u) {
                int h = h4 * 4 + u;
                ((float*)&sWT[h][(c >> 2) ^ (h & 7)])[c & 3] = (&v.x)[u];
            }
        }
    }
    sx[wid][0][lane] = xa;
    sx[wid][1][lane] = xb;

    // --- sum of weights per node: reduce within each 32-lane half ---
    float s32 = w;
    #pragma unroll
    for (int off = 16; off; off >>= 1) s32 += __shfl_xor(s32, off);
    const float sumwa = __shfl(s32, 0);
    const float sumwb = __shfl(s32, 32);

    // --- neighbor aggregation: ids/weights broadcast via shfl ---
    float agga = 0.f, aggb = 0.f;
    #pragma unroll 8
    for (int k = 0; k < KN; ++k) {
        int   ia = __shfl(id, k);
        float wa = __shfl(w,  k);
        int   ib = __shfl(id, 32 + k);
        float wv = __shfl(w,  32 + k);
        agga = fmaf(wa, Hbuf[(size_t)ia * 64 + lane], agga);
        aggb = fmaf(wv, Hbuf[(size_t)ib * 64 + lane], aggb);
    }
    sa[wid][0][lane] = agga / (sumwa + 1e-6f);
    sa[wid][1][lane] = aggb / (sumwb + 1e-6f);
    __syncthreads();   // sWT staged (sx/sa are wave-local)

    // --- combine GEMV: both nodes share each W^T read ---
    const float4* x4a = (const float4*)sx[wid][0];
    const float4* x4b = (const float4*)sx[wid][1];
    const float4* a4a = (const float4*)sa[wid][0];
    const float4* a4b = (const float4*)sa[wid][1];

    const float wb = Wb[lane];
    float acca = wb, accb = wb;
    #pragma unroll
    for (int c4 = 0; c4 < 16; ++c4) {
        float4 wv = sWT[lane][c4 ^ (lane & 7)];
        float4 va = x4a[c4], vb = x4b[c4];
        #pragma unroll
        for (int u = 0; u < 4; ++u) {
            acca = fmaf((&va.x)[u], (&wv.x)[u], acca);
            accb = fmaf((&vb.x)[u], (&wv.x)[u], accb);
        }
    }
    #pragma unroll
    for (int c4 = 0; c4 < 16; ++c4) {
        float4 wv = sWT[lane][(16 + c4) ^ (lane & 7)];
        float4 va = a4a[c4], vb = a4b[c4];
        #pragma unroll
        for (int u = 0; u < 4; ++u) {
            acca = fmaf((&va.x)[u], (&wv.x)[u], acca);
            accb = fmaf((&vb.x)[u], (&wv.x)[u], accb);
        }
    }

    // --- leaky + L2 normalize (per node: reduce across full wave) ---
    float oa = leaky_f(acca), ob = leaky_f(accb);
    float ssa = oa * oa, ssb = ob * ob;
    #pragma unroll
    for (int off = 32; off; off >>= 1) {
        ssa += __shfl_xor(ssa, off);
        ssb += __shfl_xor(ssb, off);
    }
    const float ona = oa / (sqrtf(ssa) + 1e-6f);
    const float onb = ob / (sqrtf(ssb) + 1e-6f);
    if (na < N) OUT[(size_t)na * 64 + lane] = ona;
    if (nb < N) OUT[(size_t)nb * 64 + lane] = onb;

    if (FUSE) {
        float acc1a = Q1b[lane], acc1b = acc1a;
        #pragma unroll 8
        for (int c = 0; c < 64; ++c) {
            float q = Q1w[c * 64 + lane];    // L1-resident, shared by both nodes
            acc1a = fmaf(__shfl(ona, c), q, acc1a);
            acc1b = fmaf(__shfl(onb, c), q, acc1b);
        }
        if (na < N) H1out[(size_t)na * 64 + lane] = leaky_f(acc1a);
        if (nb < N) H1out[(size_t)nb * 64 + lane] = leaky_f(acc1b);
    }
}

extern "C" void kernel_launch(void* const* d_in, const int* in_sizes, int n_in,
                              void* d_out, int out_size, void* d_ws, size_t ws_size,
                              hipStream_t stream)
{
    const float* emb  = (const float*)d_in[0];  // (1, N, 64)
    const float* wmat = (const float*)d_in[1];  // (N, N)
    const int*   nbr  = (const int*)  d_in[2];  // (N, 32) int32
    const float* Q0w  = (const float*)d_in[3];
    const float* Q0b  = (const float*)d_in[4];
    const float* W0w  = (const float*)d_in[5];
    const float* W0b  = (const float*)d_in[6];
    const float* Q1w  = (const float*)d_in[7];
    const float* Q1b  = (const float*)d_in[8];
    const float* W1w  = (const float*)d_in[9];
    const float* W1b  = (const float*)d_in[10];
    float* out = (float*)d_out;

    const int N = in_sizes[2] / KN;             // 12000
    const size_t hbuf_bytes = (size_t)N * 64 * sizeof(float);
    const size_t wc_bytes   = (size_t)N * KN * sizeof(float);

    float* h0 = (float*)d_ws;
    float* h1 = (float*)((char*)d_ws + hbuf_bytes);
    bool use_wc = ws_size >= 2 * hbuf_bytes + wc_bytes;
    float* wcache = use_wc ? (float*)((char*)d_ws + 2 * hbuf_bytes) : nullptr;
    const int mode = use_wc ? 1 : 0;

    const int gridA = (N + 15) / 16;   // 750
    const int gridC = (N + 7) / 8;     // 1500

    // K_A: h0 + wcache (gather overlapped with dense GEMV)
    k_dense_gather<<<gridA, 256, 0, stream>>>(emb, Q0w, Q0b, wmat, nbr,
                                              wcache, h0, N);
    // K_B: layer-0 conv (+ fused layer-1 dense): emb,h0 -> out0, h1
    k_conv<true><<<gridC, 256, 0, stream>>>(emb, h0, wmat, wcache, nbr,
                                            W0w, W0b, Q1w, Q1b, out, h1, N, mode);
    // K_C: layer-1 conv (in-place on out)
    k_conv<false><<<gridC, 256, 0, stream>>>(out, h1, wmat, wcache, nbr,
                                             W1w, W1b, nullptr, nullptr,
                                             out, nullptr, N, mode);
}

// Round 11
// 64.615 us; speedup vs baseline: 1.1737x; 1.1737x over previous
//
#include <hip/hip_runtime.h>
#include <math.h>

#define ALPHA 0.3f
#define KN 32

__device__ __forceinline__ float leaky_f(float x) { return x >= 0.f ? x : ALPHA * x; }

// ---------------------------------------------------------------------------
// K_A: 16 nodes/block (4 waves x 4 groups):
//   h0[n,h] = leaky( sum_c emb[n,c]*Q0w[c,h] + Q0b[h] )
//   wcache[n,k] = wmat[n, nbr[n,k]]   (issued FIRST; latency hides under GEMV)
// (identical to the 64.1 µs R8 kernel)
// ---------------------------------------------------------------------------
__global__ __launch_bounds__(256) void k_dense_gather(
    const float* __restrict__ X,
    const float* __restrict__ Qw,
    const float* __restrict__ Qb,
    const float* __restrict__ wmat,
    const int*  __restrict__ nbr,
    float* __restrict__ wcache,      // may be null
    float* __restrict__ Hout,
    int N)
{
    __shared__ float sQ[64 * 64];
    __shared__ float sX[4][64];
    const int tid  = threadIdx.x;
    const int wid  = tid >> 6;
    const int lane = tid & 63;
    const int bs   = blockIdx.x * 16;

    // --- random gathers first: 512 (node,k) entries = 2 per thread ---
    int gid[2]; float gw[2];
    #pragma unroll
    for (int u = 0; u < 2; ++u) {
        int e = tid + u * 256;
        int n = bs + (e >> 5); if (n >= N) n = N - 1;
        gid[u] = nbr[(size_t)n * KN + (e & 31)];
    }
    #pragma unroll
    for (int u = 0; u < 2; ++u) {
        int e = tid + u * 256;
        int n = bs + (e >> 5); if (n >= N) n = N - 1;
        gw[u] = wmat[(size_t)n * (size_t)N + gid[u]];
    }

    // --- stage Q0 (float4, 4/thread) while gathers are in flight ---
    {
        const float4* s = (const float4*)Qw; float4* d = (float4*)sQ;
        #pragma unroll
        for (int i = 0; i < 4; ++i) d[i * 256 + tid] = s[i * 256 + tid];
    }
    __syncthreads();

    const float qb = Qb[lane];
    #pragma unroll
    for (int g = 0; g < 4; ++g) {
        int nr = bs + g * 4 + wid;
        int n  = nr < N ? nr : N - 1;
        sX[wid][lane] = X[(size_t)n * 64 + lane];   // wave-local slot
        float acc = qb;
        #pragma unroll
        for (int c = 0; c < 64; ++c)
            acc = fmaf(sX[wid][c], sQ[c * 64 + lane], acc);
        if (nr < N) Hout[(size_t)n * 64 + lane] = leaky_f(acc);
    }

    // --- persist gathered weights (coalesced) ---
    if (wcache) {
        #pragma unroll
        for (int u = 0; u < 2; ++u) {
            int e = tid + u * 256;
            if (bs + (e >> 5) < N) wcache[(size_t)bs * KN + e] = gw[u];
        }
    }
}

// ---------------------------------------------------------------------------
// K_B/K_C: conv layer, 16 nodes/block = 4 waves x 4 sequential groups.
// (R8 structure; only NPB 8->16 so grid=750 -> one occupancy round @3 blk/CU,
//  W staged once per 16 nodes. Rolling register prefetch of next group.)
//   w_k from wcache (mode 1) or wmat gather (mode 0 fallback)
//   agg = sum_k w_k*Hbuf[nbr,:] / (sum_k w_k + 1e-6)
//   o = leaky([x,agg].Ww + Wb);  OUT[n] = o/(||o||+1e-6)
//   FUSE: H1out[n] = leaky(OUT[n].Q1w + Q1b)  (node-local; Q1w L1-resident)
// In-place safe (OUT may alias X): wave reads its own X row before writing.
// ---------------------------------------------------------------------------
template<bool FUSE>
__global__ __launch_bounds__(256) void k_conv(
    const float* __restrict__ X,
    const float* __restrict__ Hbuf,
    const float* __restrict__ Wmat,
    const float* __restrict__ wcache,
    const int*  __restrict__ nbr,
    const float* __restrict__ Ww,    // 128 x 64
    const float* __restrict__ Wb,
    const float* __restrict__ Q1w,   // 64 x 64 (FUSE)
    const float* __restrict__ Q1b,   // 64     (FUSE)
    float* __restrict__ OUT,
    float* __restrict__ H1out,
    int N, int mode)
{
    __shared__ float sW[128 * 64];   // 32 KB
    __shared__ float sw[4][32];
    __shared__ int   snb[4][32];
    __shared__ float sx[4][64];
    __shared__ float sa[4][64];      // 35 KB total

    const int tid  = threadIdx.x;
    const int wid  = tid >> 6;
    const int lane = tid & 63;
    const int bs   = blockIdx.x * 16;

    // --- group-0 loads first (overlap with W staging) ---
    int n0 = bs + wid; if (n0 >= N) n0 = N - 1;
    float x0 = X[(size_t)n0 * 64 + lane];
    int id0 = 0; float wv0 = 0.f;
    if (lane < KN) {
        id0 = nbr[(size_t)n0 * KN + lane];
        wv0 = (mode == 1) ? wcache[(size_t)n0 * KN + lane]
                          : Wmat[(size_t)n0 * (size_t)N + id0];
    }

    // --- stage Ww (float4, 8/thread) ---
    {
        const float4* s = (const float4*)Ww; float4* d = (float4*)sW;
        #pragma unroll
        for (int i = 0; i < 8; ++i) d[i * 256 + tid] = s[i * 256 + tid];
    }
    sx[wid][lane] = x0;
    if (lane < KN) { snb[wid][lane] = id0; sw[wid][lane] = wv0; }
    __syncthreads();   // sW ready (sx/sw/snb are wave-local)

    const float wb = Wb[lane];
    const float qb = FUSE ? Q1b[lane] : 0.f;

    float xn = 0.f; int idn = 0; float wvn = 0.f;   // next-group prefetch regs

    #pragma unroll
    for (int g = 0; g < 4; ++g) {
        const int nr = bs + g * 4 + wid;

        if (g < 3) {
            // prefetch next group into registers; drains under this group's compute
            int n1 = bs + (g + 1) * 4 + wid; if (n1 >= N) n1 = N - 1;
            xn = X[(size_t)n1 * 64 + lane];
            if (lane < KN) {
                idn = nbr[(size_t)n1 * KN + lane];
                wvn = (mode == 1) ? wcache[(size_t)n1 * KN + lane]
                                  : Wmat[(size_t)n1 * (size_t)N + idn];
            }
        }

        // --- neighbor aggregation (wave-local LDS) ---
        float sumw = 0.f;
        #pragma unroll
        for (int k = 0; k < KN; ++k) sumw += sw[wid][k];

        float agg = 0.f;
        #pragma unroll 8
        for (int k = 0; k < KN; ++k) {
            size_t id = (size_t)snb[wid][k];
            agg = fmaf(sw[wid][k], Hbuf[id * 64 + lane], agg);
        }
        sa[wid][lane] = agg / (sumw + 1e-6f);

        // --- combine GEMV ---
        float acc = wb;
        #pragma unroll
        for (int c = 0; c < 64; ++c)
            acc = fmaf(sx[wid][c], sW[c * 64 + lane], acc);
        #pragma unroll
        for (int c = 0; c < 64; ++c)
            acc = fmaf(sa[wid][c], sW[(64 + c) * 64 + lane], acc);

        float o = leaky_f(acc);
        float ss = o * o;
        #pragma unroll
        for (int off = 32; off; off >>= 1) ss += __shfl_xor(ss, off);
        const float on = o / (sqrtf(ss) + 1e-6f);
        if (nr < N) OUT[(size_t)nr * 64 + lane] = on;

        if (FUSE) {
            float acc1 = qb;
            #pragma unroll 8
            for (int c = 0; c < 64; ++c)
                acc1 = fmaf(__shfl(on, c), Q1w[c * 64 + lane], acc1);
            if (nr < N) H1out[(size_t)nr * 64 + lane] = leaky_f(acc1);
        }

        if (g < 3) {
            // install next group's inputs (wave-local slots; no block barrier)
            sx[wid][lane] = xn;
            if (lane < KN) { snb[wid][lane] = idn; sw[wid][lane] = wvn; }
        }
    }
}

extern "C" void kernel_launch(void* const* d_in, const int* in_sizes, int n_in,
                              void* d_out, int out_size, void* d_ws, size_t ws_size,
                              hipStream_t stream)
{
    const float* emb  = (const float*)d_in[0];  // (1, N, 64)
    const float* wmat = (const float*)d_in[1];  // (N, N)
    const int*   nbr  = (const int*)  d_in[2];  // (N, 32) int32
    const float* Q0w  = (const float*)d_in[3];
    const float* Q0b  = (const float*)d_in[4];
    const float* W0w  = (const float*)d_in[5];
    const float* W0b  = (const float*)d_in[6];
    const float* Q1w  = (const float*)d_in[7];
    const float* Q1b  = (const float*)d_in[8];
    const float* W1w  = (const float*)d_in[9];
    const float* W1b  = (const float*)d_in[10];
    float* out = (float*)d_out;

    const int N = in_sizes[2] / KN;             // 12000
    const size_t hbuf_bytes = (size_t)N * 64 * sizeof(float);
    const size_t wc_bytes   = (size_t)N * KN * sizeof(float);

    float* h0 = (float*)d_ws;
    float* h1 = (float*)((char*)d_ws + hbuf_bytes);
    bool use_wc = ws_size >= 2 * hbuf_bytes + wc_bytes;
    float* wcache = use_wc ? (float*)((char*)d_ws + 2 * hbuf_bytes) : nullptr;
    const int mode = use_wc ? 1 : 0;

    const int gridA = (N + 15) / 16;   // 750
    const int gridC = (N + 15) / 16;   // 750

    // K_A: h0 + wcache (gather overlapped with dense GEMV)
    k_dense_gather<<<gridA, 256, 0, stream>>>(emb, Q0w, Q0b, wmat, nbr,
                                              wcache, h0, N);
    // K_B: layer-0 conv (+ fused layer-1 dense): emb,h0 -> out0, h1
    k_conv<true><<<gridC, 256, 0, stream>>>(emb, h0, wmat, wcache, nbr,
                                            W0w, W0b, Q1w, Q1b, out, h1, N, mode);
    // K_C: layer-1 conv (in-place on out)
    k_conv<false><<<gridC, 256, 0, stream>>>(out, h1, wmat, wcache, nbr,
                                             W1w, W1b, nullptr, nullptr,
                                             out, nullptr, N, mode);
}